// Round 6
// baseline (173.731 us; speedup 1.0000x reference)
//
#include <hip/hip_runtime.h>
#include <hip/hip_bf16.h>
#include <stdint.h>
#include <stddef.h>

typedef __bf16 bf16;
typedef __attribute__((ext_vector_type(4))) __bf16 bf16x4;
typedef __attribute__((ext_vector_type(8))) __bf16 bf16x8;
typedef __attribute__((ext_vector_type(4))) float f32x4;

#define BATCH 4096
#define DIM 1024
#define ODIM 1024
#define K3 3072

// workspace layout (bytes) — P intermediate eliminated (powers fused into GEMM)
#define WS_CB     0           // bf16 [1024][3072] = 6291456
#define WS_BIAS   6291456     // f32  [1024]
#define WS_PMIN   6295552     // f32  [256][1024] = 1048576
#define WS_PMAX   7344128     // f32  [256][1024]
#define WS_MINV   8392704     // f32  [1024]
#define WS_SCALE  8396800     // f32  [1024]

#define BARRIER()                     \
  do {                                \
    asm volatile("" ::: "memory");    \
    __builtin_amdgcn_s_barrier();     \
    asm volatile("" ::: "memory");    \
  } while (0)
// lgkmcnt(0), vmcnt/expcnt no-wait: vm[3:0]=15,exp=7,lgkm=0,vm[5:4]=3
#define WAIT_LGKM() __builtin_amdgcn_s_waitcnt(0xC07F)

// ---- kernel 1 (FUSED): blocks 0..255  = per-chunk column min/max of x
//                        blocks 256..1279 = spline coeff reduce (independent)
// The two cold HBM streams (x: 16.8 MB, sp: 67 MB) run CONCURRENTLY.
__global__ void k_stream(const float* __restrict__ x,
                         float* __restrict__ pmin,
                         float* __restrict__ pmax,
                         const float* __restrict__ sp,
                         bf16* __restrict__ CB,
                         float* __restrict__ bias) {
  __shared__ float red[4];
  const int t = threadIdx.x;
  if (blockIdx.x < 256) {
    const int ch = blockIdx.x;
    const float* p = x + (size_t)ch * 16 * DIM + (t << 2);
    f32x4 mn = {1e30f, 1e30f, 1e30f, 1e30f};
    f32x4 mx = {-1e30f, -1e30f, -1e30f, -1e30f};
#pragma unroll
    for (int r = 0; r < 16; ++r) {
      f32x4 v = *(const f32x4*)(p + (size_t)r * DIM);
#pragma unroll
      for (int j = 0; j < 4; ++j) {
        mn[j] = fminf(mn[j], v[j]);
        mx[j] = fmaxf(mx[j], v[j]);
      }
    }
    *(f32x4*)(pmin + ch * DIM + (t << 2)) = mn;
    *(f32x4*)(pmax + ch * DIM + (t << 2)) = mx;
  } else {
    const int o = blockIdx.x - 256;
    const int d = t << 2;
    f32x4 s[4];
#pragma unroll
    for (int dd = 0; dd < 4; ++dd) {
      const float* p = sp + ((size_t)o * DIM + d + dd) * 16;  // [s=4][4]
      f32x4 acc = *(const f32x4*)(p);
      acc += *(const f32x4*)(p + 4);
      acc += *(const f32x4*)(p + 8);
      acc += *(const f32x4*)(p + 12);
      s[dd] = acc;
    }
    size_t cb = (size_t)o * K3 + d;
    bf16x4 c0 = {(bf16)s[0][0], (bf16)s[1][0], (bf16)s[2][0], (bf16)s[3][0]};
    bf16x4 c1 = {(bf16)s[0][1], (bf16)s[1][1], (bf16)s[2][1], (bf16)s[3][1]};
    bf16x4 c2 = {(bf16)s[0][2], (bf16)s[1][2], (bf16)s[2][2], (bf16)s[3][2]};
    *(bf16x4*)(CB + cb) = c0;
    *(bf16x4*)(CB + cb + 1024) = c1;
    *(bf16x4*)(CB + cb + 2048) = c2;
    float v = s[0][3] + s[1][3] + s[2][3] + s[3][3];
#pragma unroll
    for (int off = 32; off > 0; off >>= 1) v += __shfl_down(v, off, 64);
    int lane = t & 63, w = t >> 6;
    if (lane == 0) red[w] = v;
    __syncthreads();
    if (t == 0) bias[o] = red[0] + red[1] + red[2] + red[3];
  }
}

// ---- kernel 2: final reduce + scale (16 blocks x 4 waves, coalesced) ----
__global__ void k_minmax_final(const float* __restrict__ pmin,
                               const float* __restrict__ pmax,
                               float* __restrict__ minv,
                               float* __restrict__ scale) {
  __shared__ float smn[4][64], smx[4][64];
  const int t = threadIdx.x;
  const int lane = t & 63;
  const int w = t >> 6;
  const int col = blockIdx.x * 64 + lane;
  float mn = 1e30f, mx = -1e30f;
#pragma unroll 8
  for (int ch = w; ch < 256; ch += 4) {
    mn = fminf(mn, pmin[ch * DIM + col]);
    mx = fmaxf(mx, pmax[ch * DIM + col]);
  }
  smn[w][lane] = mn;
  smx[w][lane] = mx;
  __syncthreads();
  if (w == 0) {
    mn = fminf(fminf(smn[0][lane], smn[1][lane]), fminf(smn[2][lane], smn[3][lane]));
    mx = fmaxf(fmaxf(smx[0][lane], smx[1][lane]), fmaxf(smx[2][lane], smx[3][lane]));
    minv[col] = mn;
    scale[col] = 1.0f / (mx - mn);
  }
}

// ---- kernel 3: FUSED powers+GEMM. out[b][o] = sum_p sum_d pow_p(xn[b][d]) * CB[o][p*1024+d] + bias[o]
// 128x128 tile, 8 waves (512 thr), wave tile 64x32.
// A (3 power sub-tiles [128][64] bf16, XOR-swizzled) generated IN-KERNEL from
// x f32 tile: load x -> normalize (minv/scale from LDS) -> x,x2,x3 -> ds_write.
// Double-buffered A -> ONE barrier per dim-tile. B frags read DIRECT from
// global (L2-resident per-XCD thanks to swizzle): no B staging, no vmcnt
// bookkeeping, and LDS read traffic ~halved (LDS BW was the binding resource).
#define MSOFF 98304            // minv[1024]f32 | scale[1024]f32 after 2 A bufs
#define ABUF(b) ((b) * 49152)  // [3][128][64] bf16 per buffer
__global__ __launch_bounds__(512, 2) void k_gemm(const float* __restrict__ x,
                                                 const float* __restrict__ minv,
                                                 const float* __restrict__ scale,
                                                 const bf16* __restrict__ CBm,
                                                 const float* __restrict__ bias,
                                                 float* __restrict__ out) {
  __shared__ __attribute__((aligned(16))) char smem[106496];  // 104 KB

  const int tid = threadIdx.x;
  const int wave = tid >> 6;
  const int lane = tid & 63;

  // XCD-chunk decode: bijective map flat bid -> (mt, nt) in 32x8 tile grid
  const int f = blockIdx.x;
  const int chunk = f & 7;       // lands on XCD (f % 8)
  const int idx = f >> 3;        // 0..31 within chunk
  const int mt = ((chunk >> 1) << 3) + (idx >> 2);
  const int nt = ((chunk & 1) << 2) + (idx & 3);
  const int bm = mt * 128;
  const int bn = nt * 128;

  const int wr = (wave >> 2) * 64;  // wave row origin (M): 0 or 64
  const int wc = (wave & 3) * 32;   // wave col origin (N): 0..96
  const int mrow = lane & 15;
  const int kq = lane >> 4;         // 16B-unit within 32-elem k-window

  // powers-producer mapping: thread -> (row, 16 dims)
  const int prow = tid >> 2;        // 0..127
  const int cq = tid & 3;
  const int c0 = cq << 4;           // dim offset within 64-dim tile
  const int s0 = (((cq << 1)) ^ (prow & 7)) << 4;      // swizzled byte slot, lo 8 dims
  const int s1 = (((cq << 1) | 1) ^ (prow & 7)) << 4;  // hi 8 dims

  const float* xg = x + (size_t)(bm + prow) * DIM + c0;

  // stage minv|scale into LDS (8 KB)
  if (tid < 256) {
    f32x4 m = *(const f32x4*)(minv + tid * 4);
    *(f32x4*)(smem + MSOFF + tid * 16) = m;
  } else {
    f32x4 s = *(const f32x4*)(scale + (tid - 256) * 4);
    *(f32x4*)(smem + MSOFF + 4096 + (tid - 256) * 16) = s;
  }

  f32x4 xv0, xv1, xv2, xv3;
#define LOADX(dtv)                                                            \
  do {                                                                        \
    const float* xp_ = xg + (dtv) * 64;                                       \
    xv0 = *(const f32x4*)(xp_);                                               \
    xv1 = *(const f32x4*)(xp_ + 4);                                           \
    xv2 = *(const f32x4*)(xp_ + 8);                                           \
    xv3 = *(const f32x4*)(xp_ + 12);                                          \
  } while (0)

#define POWERS_WRITE(abuf, dtv)                                               \
  do {                                                                        \
    const char* ms_ = smem + MSOFF + ((dtv) * 64 + c0) * 4;                   \
    f32x4 xn0 = (xv0 - *(const f32x4*)(ms_)) * *(const f32x4*)(ms_ + 4096);   \
    f32x4 xn1 = (xv1 - *(const f32x4*)(ms_ + 16)) * *(const f32x4*)(ms_ + 4112); \
    f32x4 xn2 = (xv2 - *(const f32x4*)(ms_ + 32)) * *(const f32x4*)(ms_ + 4128); \
    f32x4 xn3 = (xv3 - *(const f32x4*)(ms_ + 48)) * *(const f32x4*)(ms_ + 4144); \
    f32x4 x20 = xn0 * xn0, x21 = xn1 * xn1, x22 = xn2 * xn2, x23 = xn3 * xn3; \
    f32x4 x30 = x20 * xn0, x31 = x21 * xn1, x32 = x22 * xn2, x33 = x23 * xn3; \
    bf16x8 w3lo, w3hi, w2lo, w2hi, w1lo, w1hi;                                \
    _Pragma("unroll") for (int e = 0; e < 4; ++e) {                           \
      w3lo[e] = (bf16)x30[e]; w3lo[e + 4] = (bf16)x31[e];                     \
      w3hi[e] = (bf16)x32[e]; w3hi[e + 4] = (bf16)x33[e];                     \
      w2lo[e] = (bf16)x20[e]; w2lo[e + 4] = (bf16)x21[e];                     \
      w2hi[e] = (bf16)x22[e]; w2hi[e + 4] = (bf16)x23[e];                     \
      w1lo[e] = (bf16)xn0[e]; w1lo[e + 4] = (bf16)xn1[e];                     \
      w1hi[e] = (bf16)xn2[e]; w1hi[e + 4] = (bf16)xn3[e];                     \
    }                                                                         \
    char* aw_ = smem + ABUF(abuf) + prow * 128;                               \
    *(bf16x8*)(aw_ + s0) = w3lo;                                              \
    *(bf16x8*)(aw_ + s1) = w3hi;                                              \
    *(bf16x8*)(aw_ + 16384 + s0) = w2lo;                                      \
    *(bf16x8*)(aw_ + 16384 + s1) = w2hi;                                      \
    *(bf16x8*)(aw_ + 32768 + s0) = w1lo;                                      \
    *(bf16x8*)(aw_ + 32768 + s1) = w1hi;                                      \
  } while (0)

  f32x4 acc[4][2] = {};
  // per-thread B base: CB row (bn + wc + mrow), k-unit kq
  const char* cbT = (const char*)CBm + (size_t)(bn + wc + mrow) * 6144 + kq * 16;

#define COMPUTE(abuf, dtv)                                                    \
  do {                                                                        \
    _Pragma("unroll") for (int p = 0; p < 3; ++p) {                           \
      const char* cb_ = cbT + p * 2048 + (dtv) * 128;                         \
      bf16x8 bg[2][2];                                                        \
      _Pragma("unroll") for (int j = 0; j < 2; ++j)                           \
        _Pragma("unroll") for (int ks = 0; ks < 2; ++ks)                      \
            bg[j][ks] = *(const bf16x8*)(cb_ + (size_t)j * 16 * 6144 + ks * 64); \
      const char* ab_ = smem + ABUF(abuf) + p * 16384;                        \
      _Pragma("unroll") for (int ks = 0; ks < 2; ++ks) {                      \
        bf16x8 af[4];                                                         \
        _Pragma("unroll") for (int i = 0; i < 4; ++i) {                       \
          int row_ = wr + i * 16 + mrow;                                      \
          int su_ = ((ks * 4 + kq) ^ (row_ & 7)) * 16;                        \
          af[i] = *(const bf16x8*)(ab_ + row_ * 128 + su_);                   \
        }                                                                     \
        _Pragma("unroll") for (int i = 0; i < 4; ++i)                         \
            _Pragma("unroll") for (int j = 0; j < 2; ++j)                     \
                acc[i][j] = __builtin_amdgcn_mfma_f32_16x16x32_bf16(          \
                    af[i], bg[j][ks], acc[i][j], 0, 0, 0);                    \
      }                                                                       \
    }                                                                         \
  } while (0)

  // prologue
  LOADX(0);
  WAIT_LGKM();
  BARRIER();           // minv/scale visible
  POWERS_WRITE(0, 0);  // compiler waits x(0) vmcnt before use
  LOADX(1);
  WAIT_LGKM();
  BARRIER();           // A(0) published

#pragma unroll 2
  for (int dt = 0; dt < 15; ++dt) {
    COMPUTE(dt & 1, dt);               // reads A[dt&1] + B direct from L2
    POWERS_WRITE((dt + 1) & 1, dt + 1);// write other buffer (no read conflict)
    if (dt < 14) LOADX(dt + 2);        // prefetch next x tile (T14 issue-early)
    WAIT_LGKM();                       // own ds_writes drained
    BARRIER();                         // A(dt+1) published; all done with A(dt)
  }
  COMPUTE(1, 15);

  // epilogue: C/D layout col=lane&15, row=(lane>>4)*4+reg
  const int ccol = lane & 15;
  const int crow = (lane >> 4) * 4;
#pragma unroll
  for (int j = 0; j < 2; ++j) {
    const int col = bn + wc + j * 16 + ccol;
    const float bv = bias[col];
#pragma unroll
    for (int i = 0; i < 4; ++i) {
      const int row0 = bm + wr + i * 16 + crow;
#pragma unroll
      for (int r = 0; r < 4; ++r)
        out[(size_t)(row0 + r) * ODIM + col] = acc[i][j][r] + bv;
    }
  }
#undef LOADX
#undef POWERS_WRITE
#undef COMPUTE
}

extern "C" void kernel_launch(void* const* d_in, const int* in_sizes, int n_in,
                              void* d_out, int out_size, void* d_ws, size_t ws_size,
                              hipStream_t stream) {
  (void)in_sizes; (void)n_in; (void)out_size; (void)ws_size;
  const float* x = (const float*)d_in[0];
  const float* sp = (const float*)d_in[1];
  float* out = (float*)d_out;
  char* ws = (char*)d_ws;

  bf16* CBm = (bf16*)(ws + WS_CB);
  float* bias = (float*)(ws + WS_BIAS);
  float* pmin = (float*)(ws + WS_PMIN);
  float* pmax = (float*)(ws + WS_PMAX);
  float* minv = (float*)(ws + WS_MINV);
  float* scale = (float*)(ws + WS_SCALE);

  // k_stream overlaps the two independent cold HBM reads (x and sp)
  k_stream<<<1280, 256, 0, stream>>>(x, pmin, pmax, sp, CBm, bias);
  k_minmax_final<<<16, 256, 0, stream>>>(pmin, pmax, minv, scale);
  k_gemm<<<256, 512, 0, stream>>>(x, minv, scale, CBm, bias, out);
}

// Round 7
// 151.533 us; speedup vs baseline: 1.1465x; 1.1465x over previous
//
#include <hip/hip_runtime.h>
#include <hip/hip_bf16.h>
#include <stdint.h>
#include <stddef.h>

typedef __bf16 bf16;
typedef __attribute__((ext_vector_type(4))) __bf16 bf16x4;
typedef __attribute__((ext_vector_type(8))) __bf16 bf16x8;
typedef __attribute__((ext_vector_type(4))) float f32x4;

#define BATCH 4096
#define DIM 1024
#define ODIM 1024
#define K3 3072

// workspace layout (bytes) — P intermediate eliminated (powers fused into GEMM)
#define WS_CB     0           // bf16 [1024][3072] = 6291456
#define WS_BIAS   6291456     // f32  [1024]
#define WS_PMIN   6295552     // f32  [256][1024] = 1048576
#define WS_PMAX   7344128     // f32  [256][1024]
#define WS_MINV   8392704     // f32  [1024]
#define WS_SCALE  8396800     // f32  [1024]

#define ASYNC16(g, l)                                                          \
  __builtin_amdgcn_global_load_lds(                                            \
      (__attribute__((address_space(1))) void*)(g),                            \
      (__attribute__((address_space(3))) void*)(l), 16, 0, 0)

#define BARRIER()                     \
  do {                                \
    asm volatile("" ::: "memory");    \
    __builtin_amdgcn_s_barrier();     \
    asm volatile("" ::: "memory");    \
  } while (0)
// wait all vmcnt; lgkm/exp no-wait: vm[3:0]=0,exp=7,lgkm=15,vm[5:4]=0
#define WAIT_VM0() __builtin_amdgcn_s_waitcnt(0x0F00 | 0x0070)
// wait lgkmcnt(0); vmcnt/expcnt no-wait
#define WAIT_LGKM() __builtin_amdgcn_s_waitcnt(0xC07F)

// ---- kernel 1 (FUSED): blocks 0..255  = per-chunk column min/max of x
//                        blocks 256..1279 = spline coeff reduce (independent)
// The two cold HBM streams (x: 16.8 MB, sp: 67 MB) run CONCURRENTLY.
__global__ void k_stream(const float* __restrict__ x,
                         float* __restrict__ pmin,
                         float* __restrict__ pmax,
                         const float* __restrict__ sp,
                         bf16* __restrict__ CB,
                         float* __restrict__ bias) {
  __shared__ float red[4];
  const int t = threadIdx.x;
  if (blockIdx.x < 256) {
    const int ch = blockIdx.x;
    const float* p = x + (size_t)ch * 16 * DIM + (t << 2);
    f32x4 mn = {1e30f, 1e30f, 1e30f, 1e30f};
    f32x4 mx = {-1e30f, -1e30f, -1e30f, -1e30f};
#pragma unroll
    for (int r = 0; r < 16; ++r) {
      f32x4 v = *(const f32x4*)(p + (size_t)r * DIM);
#pragma unroll
      for (int j = 0; j < 4; ++j) {
        mn[j] = fminf(mn[j], v[j]);
        mx[j] = fmaxf(mx[j], v[j]);
      }
    }
    *(f32x4*)(pmin + ch * DIM + (t << 2)) = mn;
    *(f32x4*)(pmax + ch * DIM + (t << 2)) = mx;
  } else {
    const int o = blockIdx.x - 256;
    const int d = t << 2;
    f32x4 s[4];
#pragma unroll
    for (int dd = 0; dd < 4; ++dd) {
      const float* p = sp + ((size_t)o * DIM + d + dd) * 16;  // [s=4][4]
      f32x4 acc = *(const f32x4*)(p);
      acc += *(const f32x4*)(p + 4);
      acc += *(const f32x4*)(p + 8);
      acc += *(const f32x4*)(p + 12);
      s[dd] = acc;
    }
    size_t cb = (size_t)o * K3 + d;
    bf16x4 c0 = {(bf16)s[0][0], (bf16)s[1][0], (bf16)s[2][0], (bf16)s[3][0]};
    bf16x4 c1 = {(bf16)s[0][1], (bf16)s[1][1], (bf16)s[2][1], (bf16)s[3][1]};
    bf16x4 c2 = {(bf16)s[0][2], (bf16)s[1][2], (bf16)s[2][2], (bf16)s[3][2]};
    *(bf16x4*)(CB + cb) = c0;
    *(bf16x4*)(CB + cb + 1024) = c1;
    *(bf16x4*)(CB + cb + 2048) = c2;
    float v = s[0][3] + s[1][3] + s[2][3] + s[3][3];
#pragma unroll
    for (int off = 32; off > 0; off >>= 1) v += __shfl_down(v, off, 64);
    int lane = t & 63, w = t >> 6;
    if (lane == 0) red[w] = v;
    __syncthreads();
    if (t == 0) bias[o] = red[0] + red[1] + red[2] + red[3];
  }
}

// ---- kernel 2: final reduce + scale (16 blocks x 4 waves, coalesced) ----
__global__ void k_minmax_final(const float* __restrict__ pmin,
                               const float* __restrict__ pmax,
                               float* __restrict__ minv,
                               float* __restrict__ scale) {
  __shared__ float smn[4][64], smx[4][64];
  const int t = threadIdx.x;
  const int lane = t & 63;
  const int w = t >> 6;
  const int col = blockIdx.x * 64 + lane;
  float mn = 1e30f, mx = -1e30f;
#pragma unroll 8
  for (int ch = w; ch < 256; ch += 4) {
    mn = fminf(mn, pmin[ch * DIM + col]);
    mx = fmaxf(mx, pmax[ch * DIM + col]);
  }
  smn[w][lane] = mn;
  smx[w][lane] = mx;
  __syncthreads();
  if (w == 0) {
    mn = fminf(fminf(smn[0][lane], smn[1][lane]), fminf(smn[2][lane], smn[3][lane]));
    mx = fmaxf(fmaxf(smx[0][lane], smx[1][lane]), fmaxf(smx[2][lane], smx[3][lane]));
    minv[col] = mn;
    scale[col] = 1.0f / (mx - mn);
  }
}

// ---- kernel 3: FUSED powers+GEMM, staged B.
// out[b][o] = sum_p sum_d pow_p(xn[b][d]) * CB[o][p*1024+d] + bias[o]
// 128x128 tile, 8 waves, wave tile 64x32. 32 dim-tiles of 32 dims.
// Per tile: A=[3][128][32]bf16 generated in-register from x (fused powers);
// B=[3][128][32] staged via global_load_lds (issued BEFORE compute = full
// compute phase of latency cover; vmcnt(0) only after — R6 showed direct-
// global B is latency-bound: 78us @ MfmaUtil 12%). Both double-buffered.
// Swizzle slot = kq ^ ((row>>1)&3): conflict-free frag reads AND writes.
#define MSOFF 98304            // minv[1024]f32 | scale[1024]f32
#define ABUF(b) ((b) * 24576)          // [3][128][32] bf16, plane stride 8192
#define BBUF(b) (49152 + (b) * 24576)
__global__ __launch_bounds__(512, 2) void k_gemm(const float* __restrict__ x,
                                                 const float* __restrict__ minv,
                                                 const float* __restrict__ scale,
                                                 const bf16* __restrict__ CBm,
                                                 const float* __restrict__ bias,
                                                 float* __restrict__ out) {
  __shared__ __attribute__((aligned(16))) char smem[106496];  // 104 KB

  const int tid = threadIdx.x;
  const int wave = tid >> 6;
  const int lane = tid & 63;

  // XCD-chunk decode: bijective map flat bid -> (mt, nt) in 32x8 tile grid
  const int f = blockIdx.x;
  const int chunk = f & 7;       // lands on XCD (f % 8)
  const int idx = f >> 3;        // 0..31 within chunk
  const int mt = ((chunk >> 1) << 3) + (idx >> 2);
  const int nt = ((chunk & 1) << 2) + (idx & 3);
  const int bm = mt * 128;
  const int bn = nt * 128;

  const int wr = (wave >> 2) * 64;  // wave row origin (M): 0 or 64
  const int wc = (wave & 3) * 32;   // wave col origin (N): 0..96
  const int mrow = lane & 15;
  const int kq = lane >> 4;         // 16B unit within the 32-dim K window

  // producer mapping: thread -> (row prow, 8-dim group u)
  const int prow = tid >> 2;        // 0..127
  const int u = tid & 3;            // 0..3
  const int aslot = (u ^ ((prow >> 1) & 3)) << 4;  // swizzled byte slot
  const float* xg = x + (size_t)(bm + prow) * DIM + u * 8;

  // B staging: thread covers LDS (row=tid>>2, slot=tid&3); global unit = slot ^ ((row>>1)&3)
  const char* gBp = (const char*)CBm + (size_t)(bn + (tid >> 2)) * 6144 +
                    (size_t)(((tid & 3) ^ ((tid >> 3) & 3)) << 4);

  // stage minv|scale into LDS (8 KB)
  if (tid < 256) {
    f32x4 m = *(const f32x4*)(minv + tid * 4);
    *(f32x4*)(smem + MSOFF + tid * 16) = m;
  } else {
    f32x4 s = *(const f32x4*)(scale + (tid - 256) * 4);
    *(f32x4*)(smem + MSOFF + 4096 + (tid - 256) * 16) = s;
  }

  f32x4 xa, xb;
#define LOADX(dtv)                                                            \
  do {                                                                        \
    xa = *(const f32x4*)(xg + (dtv) * 32);                                    \
    xb = *(const f32x4*)(xg + (dtv) * 32 + 4);                                \
  } while (0)

#define STAGE_B(buf, dtv)                                                     \
  do {                                                                        \
    const char* gb_ = gBp + (size_t)(dtv) * 64;                               \
    char* lb_ = smem + BBUF(buf) + wave * 1024;                               \
    ASYNC16(gb_, lb_);                                                        \
    ASYNC16(gb_ + 2048, lb_ + 8192);                                          \
    ASYNC16(gb_ + 4096, lb_ + 16384);                                         \
  } while (0)

#define POWERS_WRITE(abuf, dtv)                                               \
  do {                                                                        \
    const char* msp = smem + MSOFF + ((dtv) * 32 + u * 8) * 4;                \
    f32x4 mn0 = *(const f32x4*)(msp);                                         \
    f32x4 mn1 = *(const f32x4*)(msp + 16);                                    \
    f32x4 sc0 = *(const f32x4*)(msp + 4096);                                  \
    f32x4 sc1 = *(const f32x4*)(msp + 4112);                                  \
    f32x4 n0 = (xa - mn0) * sc0, n1 = (xb - mn1) * sc1;                       \
    f32x4 q0 = n0 * n0, q1 = n1 * n1;                                         \
    f32x4 c0v = q0 * n0, c1v = q1 * n1;                                       \
    bf16x8 w1, w2, w3;                                                        \
    _Pragma("unroll") for (int e = 0; e < 4; ++e) {                           \
      w3[e] = (bf16)c0v[e]; w3[e + 4] = (bf16)c1v[e];                         \
      w2[e] = (bf16)q0[e];  w2[e + 4] = (bf16)q1[e];                          \
      w1[e] = (bf16)n0[e];  w1[e + 4] = (bf16)n1[e];                          \
    }                                                                         \
    char* aw_ = smem + ABUF(abuf) + prow * 64 + aslot;                        \
    *(bf16x8*)(aw_) = w3;              /* plane 0: x^3 */                     \
    *(bf16x8*)(aw_ + 8192) = w2;       /* plane 1: x^2 */                     \
    *(bf16x8*)(aw_ + 16384) = w1;      /* plane 2: x   */                     \
  } while (0)

  f32x4 acc[4][2] = {};

#define COMPUTE(buf)                                                          \
  do {                                                                        \
    const char* ab_ = smem + ABUF(buf);                                       \
    const char* bb_ = smem + BBUF(buf);                                       \
    _Pragma("unroll") for (int p = 0; p < 3; ++p) {                           \
      bf16x8 bg[2];                                                           \
      _Pragma("unroll") for (int j = 0; j < 2; ++j) {                         \
        int rowb = wc + j * 16 + mrow;                                        \
        bg[j] = *(const bf16x8*)(bb_ + p * 8192 + rowb * 64 +                 \
                                 ((kq ^ ((rowb >> 1) & 3)) << 4));            \
      }                                                                       \
      bf16x8 af[4];                                                           \
      _Pragma("unroll") for (int i = 0; i < 4; ++i) {                         \
        int rowa = wr + i * 16 + mrow;                                        \
        af[i] = *(const bf16x8*)(ab_ + p * 8192 + rowa * 64 +                 \
                                 ((kq ^ ((rowa >> 1) & 3)) << 4));            \
      }                                                                       \
      _Pragma("unroll") for (int i = 0; i < 4; ++i)                           \
          _Pragma("unroll") for (int j = 0; j < 2; ++j)                       \
              acc[i][j] = __builtin_amdgcn_mfma_f32_16x16x32_bf16(            \
                  af[i], bg[j], acc[i][j], 0, 0, 0);                          \
    }                                                                         \
  } while (0)

  // prologue
  STAGE_B(0, 0);     // 3 vm
  LOADX(0);          // 2 vm
  WAIT_VM0();        // B(0)+x(0) drained (B had full issue-to-here window)
  WAIT_LGKM();       // ms writes drained
  BARRIER();         // ms + B(0) published
  POWERS_WRITE(0, 0);
  LOADX(1);
  WAIT_LGKM();
  BARRIER();         // A(0) published

#pragma unroll 2
  for (int dt = 0; dt < 32; ++dt) {
    if (dt < 31) STAGE_B((dt + 1) & 1, dt + 1);  // issue-early: covered by COMPUTE
    COMPUTE(dt & 1);
    if (dt < 31) POWERS_WRITE((dt + 1) & 1, dt + 1);  // consumes x(dt+1) regs
    WAIT_VM0();                     // B(dt+1) drained (issued ~1 compute ago)
    if (dt < 30) LOADX(dt + 2);     // next x tile; consumed next iter
    WAIT_LGKM();                    // own A ds_writes drained
    BARRIER();                      // A(dt+1), B(dt+1) published
  }

  // epilogue: C/D layout col=lane&15, row=(lane>>4)*4+reg
  const int ccol = lane & 15;
  const int crow = (lane >> 4) * 4;
#pragma unroll
  for (int j = 0; j < 2; ++j) {
    const int col = bn + wc + j * 16 + ccol;
    const float bv = bias[col];
#pragma unroll
    for (int i = 0; i < 4; ++i) {
      const int row0 = bm + wr + i * 16 + crow;
#pragma unroll
      for (int r = 0; r < 4; ++r)
        out[(size_t)(row0 + r) * ODIM + col] = acc[i][j][r] + bv;
    }
  }
#undef LOADX
#undef STAGE_B
#undef POWERS_WRITE
#undef COMPUTE
}

extern "C" void kernel_launch(void* const* d_in, const int* in_sizes, int n_in,
                              void* d_out, int out_size, void* d_ws, size_t ws_size,
                              hipStream_t stream) {
  (void)in_sizes; (void)n_in; (void)out_size; (void)ws_size;
  const float* x = (const float*)d_in[0];
  const float* sp = (const float*)d_in[1];
  float* out = (float*)d_out;
  char* ws = (char*)d_ws;

  bf16* CBm = (bf16*)(ws + WS_CB);
  float* bias = (float*)(ws + WS_BIAS);
  float* pmin = (float*)(ws + WS_PMIN);
  float* pmax = (float*)(ws + WS_PMAX);
  float* minv = (float*)(ws + WS_MINV);
  float* scale = (float*)(ws + WS_SCALE);

  // k_stream overlaps the two independent cold HBM reads (x and sp)
  k_stream<<<1280, 256, 0, stream>>>(x, pmin, pmax, sp, CBm, bias);
  k_minmax_final<<<16, 256, 0, stream>>>(pmin, pmax, minv, scale);
  k_gemm<<<256, 512, 0, stream>>>(x, minv, scale, CBm, bias, out);
}